// Round 3
// baseline (2363.022 us; speedup 1.0000x reference)
//
#include <hip/hip_runtime.h>
#include <hip/hip_bf16.h>

#define N_NODES 50000
#define E_EDGES 600000
#define IN_CH 128
#define HID 256
#define OUT_CH 64
#define NREL 8

// ---------------------------------------------------------------------------
// CSR construction (deterministic): histogram -> prefix scan -> placement ->
// per-node insertion sort by key (rel<<16 | src). Equal keys carry identical
// payloads, so fp accumulation order is bit-deterministic across replays.
// ---------------------------------------------------------------------------

__global__ void k_deg(const int* __restrict__ dst, int* __restrict__ deg) {
    int e = blockIdx.x * blockDim.x + threadIdx.x;
    if (e < E_EDGES) atomicAdd(&deg[dst[e]], 1);
}

__global__ __launch_bounds__(1024) void k_scan(const int* __restrict__ deg,
                                               int* __restrict__ offs) {
    __shared__ int wsum[16];
    __shared__ int s_carry;
    const int lane = threadIdx.x & 63;
    const int wid = threadIdx.x >> 6;
    if (threadIdx.x == 0) s_carry = 0;
    __syncthreads();
    for (int base = 0; base < N_NODES; base += 1024) {
        int i = base + threadIdx.x;
        int v = (i < N_NODES) ? deg[i] : 0;
        int incl = v;
#pragma unroll
        for (int s = 1; s < 64; s <<= 1) {
            int t = __shfl_up(incl, s);
            if (lane >= s) incl += t;
        }
        if (lane == 63) wsum[wid] = incl;
        __syncthreads();
        if (wid == 0) {
            int wv = (lane < 16) ? wsum[lane] : 0;
            int wincl = wv;
#pragma unroll
            for (int s = 1; s < 16; s <<= 1) {
                int t = __shfl_up(wincl, s);
                if (lane >= s) wincl += t;
            }
            if (lane < 16) wsum[lane] = wincl - wv;  // exclusive wave offset
        }
        __syncthreads();
        int excl = s_carry + wsum[wid] + incl - v;
        if (i < N_NODES) offs[i] = excl;
        __syncthreads();
        if (threadIdx.x == 1023) s_carry = excl + v;
        __syncthreads();
    }
    if (threadIdx.x == 0) offs[N_NODES] = E_EDGES;
}

__global__ void k_place(const int* __restrict__ src, const int* __restrict__ dst,
                        const int* __restrict__ etype, const int* __restrict__ offs,
                        int* __restrict__ cursor, int* __restrict__ ekey) {
    int e = blockIdx.x * blockDim.x + threadIdx.x;
    if (e < E_EDGES) {
        int d = dst[e];
        int p = atomicAdd(&cursor[d], 1);
        ekey[offs[d] + p] = (etype[e] << 16) | src[e];  // src < 65536
    }
}

__global__ void k_sort(const int* __restrict__ offs, int* __restrict__ ekey) {
    int i = blockIdx.x * blockDim.x + threadIdx.x;
    if (i >= N_NODES) return;
    int lo = offs[i], hi = offs[i + 1];
    for (int a = lo + 1; a < hi; a++) {
        int k = ekey[a];
        int b = a - 1;
        while (b >= lo && ekey[b] > k) { ekey[b + 1] = ekey[b]; b--; }
        ekey[b + 1] = k;
    }
}

// ---------------------------------------------------------------------------
// STACKED aggregation: one edge pass per node builds agg[i, r*CH+c] =
// mean over rel-r in-edges of x[src][c]. Edges are rel-sorted per node ->
// single running accumulator flushed on relation change (no runtime-indexed
// register arrays). Block = node, thread = channel.
// ---------------------------------------------------------------------------
template <int CH>
__global__ void k_agg_all(const float* __restrict__ xin, const int* __restrict__ offs,
                          const int* __restrict__ ekey, float* __restrict__ agg) {
    const int i = blockIdx.x;
    const int ch = threadIdx.x;
    float* row = agg + (size_t)i * (NREL * CH);
#pragma unroll
    for (int r = 0; r < NREL; r++) row[r * CH + ch] = 0.0f;
    const int lo = offs[i], hi = offs[i + 1];
    float acc = 0.0f;
    int cnt = 0, cur = -1;
    for (int e = lo; e < hi; e++) {
        int k = ekey[e];
        int r = k >> 16;
        if (r != cur) {
            if (cnt > 0) row[cur * CH + ch] = acc / (float)cnt;
            cur = r; acc = 0.0f; cnt = 0;
        }
        cnt++;
        acc += xin[(size_t)(k & 0xFFFF) * CH + ch];
    }
    if (cnt > 0) row[cur * CH + ch] = acc / (float)cnt;
}

// Fallback per-relation aggregation (small-workspace path).
template <int CH>
__global__ void k_agg(const float* __restrict__ xin, const int* __restrict__ offs,
                      const int* __restrict__ ekey, float* __restrict__ agg, int rel) {
    int i = blockIdx.x;
    int lo = offs[i], hi = offs[i + 1];
    float acc = 0.0f;
    int cnt = 0;
    for (int e = lo; e < hi; e++) {
        int k = ekey[e];
        int r = k >> 16;
        if (r < rel) continue;
        if (r > rel) break;
        cnt++;
        acc += xin[(size_t)(k & 0xFFFF) * CH + threadIdx.x];
    }
    agg[(size_t)i * CH + threadIdx.x] = (cnt > 0) ? acc / (float)cnt : 0.0f;
}

// ---------------------------------------------------------------------------
// fp32 GEMM: C[M,ncol] (op)= A[M,K] @ B[K,ncol].
// 128x128 tile, 256 threads, 8x8 micro-tile (split 4+4), BK=8. K % 8 == 0.
// MODE 0: C = bias + A@B ; MODE 1: C += A@B ; MODE 2: C = relu(C + A@B)
// ---------------------------------------------------------------------------
template <int MODE>
__global__ __launch_bounds__(256) void k_gemm(const float* __restrict__ A,
                                              const float* __restrict__ B,
                                              const float* __restrict__ bias,
                                              float* __restrict__ C, int M, int K,
                                              int ncol) {
    __shared__ __align__(16) float As[8][128];
    __shared__ __align__(16) float Bs[8][128];
    const int bm = blockIdx.x * 128;
    const int bn = blockIdx.y * 128;
    const int tid = threadIdx.x;
    const int tx = tid & 15;
    const int ty = tid >> 4;
    float acc[2][2][4][4] = {};

    const int arow = tid >> 1;         // 0..127
    const int acol = (tid & 1) * 4;    // 0 or 4
    const int brow = tid >> 5;         // 0..7
    const int bcol = (tid & 31) * 4;   // 0..124
    const bool aval = (bm + arow) < M;
    const float* Aptr = A + (size_t)(bm + arow) * K + acol;
    const float* Bptr = B + (size_t)brow * ncol + bn + bcol;

    for (int k0 = 0; k0 < K; k0 += 8) {
        float4 av = make_float4(0.f, 0.f, 0.f, 0.f);
        if (aval) av = *(const float4*)(Aptr + k0);
        float4 bv = *(const float4*)(Bptr + (size_t)k0 * ncol);
        __syncthreads();
        As[acol + 0][arow] = av.x;
        As[acol + 1][arow] = av.y;
        As[acol + 2][arow] = av.z;
        As[acol + 3][arow] = av.w;
        *(float4*)&Bs[brow][bcol] = bv;
        __syncthreads();
#pragma unroll
        for (int k = 0; k < 8; k++) {
            float a[2][4], b[2][4];
            *(float4*)a[0] = *(const float4*)&As[k][ty * 4];
            *(float4*)a[1] = *(const float4*)&As[k][64 + ty * 4];
            *(float4*)b[0] = *(const float4*)&Bs[k][tx * 4];
            *(float4*)b[1] = *(const float4*)&Bs[k][64 + tx * 4];
#pragma unroll
            for (int ri = 0; ri < 2; ri++)
#pragma unroll
                for (int i = 0; i < 4; i++)
#pragma unroll
                    for (int ci = 0; ci < 2; ci++)
#pragma unroll
                        for (int j = 0; j < 4; j++)
                            acc[ri][ci][i][j] += a[ri][i] * b[ci][j];
        }
    }

#pragma unroll
    for (int ri = 0; ri < 2; ri++) {
#pragma unroll
        for (int i = 0; i < 4; i++) {
            int row = bm + ri * 64 + ty * 4 + i;
            if (row >= M) continue;
#pragma unroll
            for (int ci = 0; ci < 2; ci++) {
                int col = bn + ci * 64 + tx * 4;
                float* cp = &C[(size_t)row * ncol + col];
                float4 v;
                v.x = acc[ri][ci][i][0];
                v.y = acc[ri][ci][i][1];
                v.z = acc[ri][ci][i][2];
                v.w = acc[ri][ci][i][3];
                if (MODE == 0) {
                    v.x += bias[col + 0];
                    v.y += bias[col + 1];
                    v.z += bias[col + 2];
                    v.w += bias[col + 3];
                } else {
                    float4 old = *(const float4*)cp;
                    v.x += old.x; v.y += old.y; v.z += old.z; v.w += old.w;
                    if (MODE == 2) {
                        v.x = fmaxf(v.x, 0.f); v.y = fmaxf(v.y, 0.f);
                        v.z = fmaxf(v.z, 0.f); v.w = fmaxf(v.w, 0.f);
                    }
                }
                *(float4*)cp = v;
            }
        }
    }
}

// ---------------------------------------------------------------------------
// Final linear [256->64] + log_softmax. 4 nodes per 256-thread block;
// each 64-lane wave owns one node (lane = class), shfl reductions.
// ---------------------------------------------------------------------------
__global__ __launch_bounds__(256) void k_final(const float* __restrict__ h,
                                               const float* __restrict__ W,
                                               const float* __restrict__ bias,
                                               float* __restrict__ out, int M) {
    __shared__ __align__(16) float hs[4][HID];
    const int nsub = threadIdx.x >> 6;
    const int c = threadIdx.x & 63;
    const int i = blockIdx.x * 4 + nsub;
    if (i < M) {
        *(float4*)&hs[nsub][c * 4] = *(const float4*)&h[(size_t)i * HID + c * 4];
    }
    __syncthreads();
    if (i >= M) return;
    float acc = bias[c];
#pragma unroll 8
    for (int k = 0; k < HID; k++) acc += hs[nsub][k] * W[k * OUT_CH + c];
    float m = acc;
#pragma unroll
    for (int s = 32; s > 0; s >>= 1) m = fmaxf(m, __shfl_xor(m, s));
    float ex = expf(acc - m);
    float sum = ex;
#pragma unroll
    for (int s = 32; s > 0; s >>= 1) sum += __shfl_xor(sum, s);
    out[(size_t)i * OUT_CH + c] = acc - m - logf(sum);
}

// ---------------------------------------------------------------------------
extern "C" void kernel_launch(void* const* d_in, const int* in_sizes, int n_in,
                              void* d_out, int out_size, void* d_ws, size_t ws_size,
                              hipStream_t stream) {
    const float* x     = (const float*)d_in[0];
    const int*   eidx  = (const int*)d_in[1];
    const int*   etype = (const int*)d_in[2];
    const float* W1    = (const float*)d_in[3];
    const float* root1 = (const float*)d_in[4];
    const float* b1    = (const float*)d_in[5];
    const float* W2    = (const float*)d_in[6];
    const float* root2 = (const float*)d_in[7];
    const float* b2    = (const float*)d_in[8];
    const float* linW  = (const float*)d_in[9];
    const float* linb  = (const float*)d_in[10];
    float* out = (float*)d_out;
    const int* src = eidx;
    const int* dst = eidx + E_EDGES;

    char* ws = (char*)d_ws;
    size_t off = 0;
    auto alloc = [&](size_t bytes) {
        size_t o = off;
        off += (bytes + 255) & ~(size_t)255;
        return ws + o;
    };
    float* h1   = (float*)alloc((size_t)N_NODES * HID * 4);
    float* h2   = (float*)alloc((size_t)N_NODES * HID * 4);
    int* deg    = (int*)alloc((size_t)N_NODES * 4);
    int* cursor = (int*)alloc((size_t)N_NODES * 4);
    int* offs   = (int*)alloc((size_t)(N_NODES + 1) * 4);
    int* ekey   = (int*)alloc((size_t)E_EDGES * 4);
    // Stacked agg buffer [N, NREL*HID] (largest use: layer 2, 409.6 MB).
    float* aggS = (float*)alloc((size_t)N_NODES * NREL * HID * 4);
    const bool stacked = (off <= ws_size);   // deterministic: ws_size fixed
    // Fallback layout fits in the stacked buffer's slot trivially.
    float* agg = aggS;                        // [N, HID] when !stacked

    hipMemsetAsync(deg, 0, (size_t)N_NODES * 4, stream);
    hipMemsetAsync(cursor, 0, (size_t)N_NODES * 4, stream);
    k_deg<<<(E_EDGES + 255) / 256, 256, 0, stream>>>(dst, deg);
    k_scan<<<1, 1024, 0, stream>>>(deg, offs);
    k_place<<<(E_EDGES + 255) / 256, 256, 0, stream>>>(src, dst, etype, offs, cursor, ekey);
    k_sort<<<(N_NODES + 255) / 256, 256, 0, stream>>>(offs, ekey);

    dim3 ggrid((N_NODES + 127) / 128, HID / 128);

    if (stacked) {
        // Layer 1: h1 = relu(x@root1 + b1 + aggS1 @ W1_stacked)
        k_gemm<0><<<ggrid, 256, 0, stream>>>(x, root1, b1, h1, N_NODES, IN_CH, HID);
        k_agg_all<IN_CH><<<N_NODES, IN_CH, 0, stream>>>(x, offs, ekey, aggS);
        k_gemm<2><<<ggrid, 256, 0, stream>>>(aggS, W1, nullptr, h1,
                                             N_NODES, NREL * IN_CH, HID);
        // Layer 2: h2 = relu(h1@root2 + b2 + aggS2 @ W2_stacked)
        k_gemm<0><<<ggrid, 256, 0, stream>>>(h1, root2, b2, h2, N_NODES, HID, HID);
        k_agg_all<HID><<<N_NODES, HID, 0, stream>>>(h1, offs, ekey, aggS);
        k_gemm<2><<<ggrid, 256, 0, stream>>>(aggS, W2, nullptr, h2,
                                             N_NODES, NREL * HID, HID);
    } else {
        // Per-relation fallback (audited round-0 path, ~157 MB workspace).
        k_gemm<0><<<ggrid, 256, 0, stream>>>(x, root1, b1, h1, N_NODES, IN_CH, HID);
        for (int r = 0; r < NREL; r++) {
            k_agg<IN_CH><<<N_NODES, IN_CH, 0, stream>>>(x, offs, ekey, agg, r);
            if (r < NREL - 1)
                k_gemm<1><<<ggrid, 256, 0, stream>>>(agg, W1 + (size_t)r * IN_CH * HID,
                                                     nullptr, h1, N_NODES, IN_CH, HID);
            else
                k_gemm<2><<<ggrid, 256, 0, stream>>>(agg, W1 + (size_t)r * IN_CH * HID,
                                                     nullptr, h1, N_NODES, IN_CH, HID);
        }
        k_gemm<0><<<ggrid, 256, 0, stream>>>(h1, root2, b2, h2, N_NODES, HID, HID);
        for (int r = 0; r < NREL; r++) {
            k_agg<HID><<<N_NODES, HID, 0, stream>>>(h1, offs, ekey, agg, r);
            if (r < NREL - 1)
                k_gemm<1><<<ggrid, 256, 0, stream>>>(agg, W2 + (size_t)r * HID * HID,
                                                     nullptr, h2, N_NODES, HID, HID);
            else
                k_gemm<2><<<ggrid, 256, 0, stream>>>(agg, W2 + (size_t)r * HID * HID,
                                                     nullptr, h2, N_NODES, HID, HID);
        }
    }

    // Final linear + log_softmax
    k_final<<<(N_NODES + 3) / 4, 256, 0, stream>>>(h2, linW, linb, out, N_NODES);
}

// Round 4
// 1924.211 us; speedup vs baseline: 1.2280x; 1.2280x over previous
//
#include <hip/hip_runtime.h>
#include <hip/hip_bf16.h>

#define N_NODES 50000
#define E_EDGES 600000
#define IN_CH 128
#define HID 256
#define OUT_CH 64
#define NREL 8

// ---------------------------------------------------------------------------
// CSR construction (deterministic): histogram -> prefix scan -> placement ->
// per-node insertion sort by key (rel<<16 | src). Equal keys carry identical
// payloads, so fp accumulation order is bit-deterministic across replays.
// ---------------------------------------------------------------------------

__global__ void k_deg(const int* __restrict__ dst, int* __restrict__ deg) {
    int e = blockIdx.x * blockDim.x + threadIdx.x;
    if (e < E_EDGES) atomicAdd(&deg[dst[e]], 1);
}

__global__ __launch_bounds__(1024) void k_scan(const int* __restrict__ deg,
                                               int* __restrict__ offs) {
    __shared__ int wsum[16];
    __shared__ int s_carry;
    const int lane = threadIdx.x & 63;
    const int wid = threadIdx.x >> 6;
    if (threadIdx.x == 0) s_carry = 0;
    __syncthreads();
    for (int base = 0; base < N_NODES; base += 1024) {
        int i = base + threadIdx.x;
        int v = (i < N_NODES) ? deg[i] : 0;
        int incl = v;
#pragma unroll
        for (int s = 1; s < 64; s <<= 1) {
            int t = __shfl_up(incl, s);
            if (lane >= s) incl += t;
        }
        if (lane == 63) wsum[wid] = incl;
        __syncthreads();
        if (wid == 0) {
            int wv = (lane < 16) ? wsum[lane] : 0;
            int wincl = wv;
#pragma unroll
            for (int s = 1; s < 16; s <<= 1) {
                int t = __shfl_up(wincl, s);
                if (lane >= s) wincl += t;
            }
            if (lane < 16) wsum[lane] = wincl - wv;  // exclusive wave offset
        }
        __syncthreads();
        int excl = s_carry + wsum[wid] + incl - v;
        if (i < N_NODES) offs[i] = excl;
        __syncthreads();
        if (threadIdx.x == 1023) s_carry = excl + v;
        __syncthreads();
    }
    if (threadIdx.x == 0) offs[N_NODES] = E_EDGES;
}

__global__ void k_place(const int* __restrict__ src, const int* __restrict__ dst,
                        const int* __restrict__ etype, const int* __restrict__ offs,
                        int* __restrict__ cursor, int* __restrict__ ekey) {
    int e = blockIdx.x * blockDim.x + threadIdx.x;
    if (e < E_EDGES) {
        int d = dst[e];
        int p = atomicAdd(&cursor[d], 1);
        ekey[offs[d] + p] = (etype[e] << 16) | src[e];  // src < 65536
    }
}

__global__ void k_sort(const int* __restrict__ offs, int* __restrict__ ekey) {
    int i = blockIdx.x * blockDim.x + threadIdx.x;
    if (i >= N_NODES) return;
    int lo = offs[i], hi = offs[i + 1];
    for (int a = lo + 1; a < hi; a++) {
        int k = ekey[a];
        int b = a - 1;
        while (b >= lo && ekey[b] > k) { ekey[b + 1] = ekey[b]; b--; }
        ekey[b + 1] = k;
    }
}

// ---------------------------------------------------------------------------
// Grouped stacked aggregation: one edge pass per node builds, for relations
// [rel0, rel0+G), agg[i, (r-rel0)*CH+c] = mean over rel-r in-edges of
// x[src][c]. Edges are rel-sorted per node -> running accumulator flushed on
// relation change (no runtime-indexed register arrays). Block=node,
// thread=channel.
// ---------------------------------------------------------------------------
template <int CH>
__global__ void k_agg_group(const float* __restrict__ xin, const int* __restrict__ offs,
                            const int* __restrict__ ekey, float* __restrict__ agg,
                            int rel0, int G) {
    const int i = blockIdx.x;
    const int ch = threadIdx.x;
    float* row = agg + (size_t)i * ((size_t)G * CH);
    for (int r = 0; r < G; r++) row[r * CH + ch] = 0.0f;
    const int lo = offs[i], hi = offs[i + 1];
    const int rend = rel0 + G;
    float acc = 0.0f;
    int cnt = 0, cur = -1;
    for (int e = lo; e < hi; e++) {
        int k = ekey[e];
        int r = k >> 16;
        if (r < rel0) continue;
        if (r >= rend) break;
        if (r != cur) {
            if (cnt > 0) row[(cur - rel0) * CH + ch] = acc / (float)cnt;
            cur = r; acc = 0.0f; cnt = 0;
        }
        cnt++;
        acc += xin[(size_t)(k & 0xFFFF) * CH + ch];
    }
    if (cnt > 0) row[(cur - rel0) * CH + ch] = acc / (float)cnt;
}

// ---------------------------------------------------------------------------
// fp32 GEMM: C[M,ncol] (op)= A[M,K] @ B[K,ncol].
// 128x128 tile, 256 threads, 8x8 micro-tile (split 4+4), BK=8. K % 8 == 0.
// MODE 0: C = bias + A@B ; MODE 1: C += A@B ; MODE 2: C = relu(C + A@B)
// ---------------------------------------------------------------------------
template <int MODE>
__global__ __launch_bounds__(256) void k_gemm(const float* __restrict__ A,
                                              const float* __restrict__ B,
                                              const float* __restrict__ bias,
                                              float* __restrict__ C, int M, int K,
                                              int ncol) {
    __shared__ __align__(16) float As[8][128];
    __shared__ __align__(16) float Bs[8][128];
    const int bm = blockIdx.x * 128;
    const int bn = blockIdx.y * 128;
    const int tid = threadIdx.x;
    const int tx = tid & 15;
    const int ty = tid >> 4;
    float acc[2][2][4][4] = {};

    const int arow = tid >> 1;         // 0..127
    const int acol = (tid & 1) * 4;    // 0 or 4
    const int brow = tid >> 5;         // 0..7
    const int bcol = (tid & 31) * 4;   // 0..124
    const bool aval = (bm + arow) < M;
    const float* Aptr = A + (size_t)(bm + arow) * K + acol;
    const float* Bptr = B + (size_t)brow * ncol + bn + bcol;

    for (int k0 = 0; k0 < K; k0 += 8) {
        float4 av = make_float4(0.f, 0.f, 0.f, 0.f);
        if (aval) av = *(const float4*)(Aptr + k0);
        float4 bv = *(const float4*)(Bptr + (size_t)k0 * ncol);
        __syncthreads();
        As[acol + 0][arow] = av.x;
        As[acol + 1][arow] = av.y;
        As[acol + 2][arow] = av.z;
        As[acol + 3][arow] = av.w;
        *(float4*)&Bs[brow][bcol] = bv;
        __syncthreads();
#pragma unroll
        for (int k = 0; k < 8; k++) {
            float a[2][4], b[2][4];
            *(float4*)a[0] = *(const float4*)&As[k][ty * 4];
            *(float4*)a[1] = *(const float4*)&As[k][64 + ty * 4];
            *(float4*)b[0] = *(const float4*)&Bs[k][tx * 4];
            *(float4*)b[1] = *(const float4*)&Bs[k][64 + tx * 4];
#pragma unroll
            for (int ri = 0; ri < 2; ri++)
#pragma unroll
                for (int i = 0; i < 4; i++)
#pragma unroll
                    for (int ci = 0; ci < 2; ci++)
#pragma unroll
                        for (int j = 0; j < 4; j++)
                            acc[ri][ci][i][j] += a[ri][i] * b[ci][j];
        }
    }

#pragma unroll
    for (int ri = 0; ri < 2; ri++) {
#pragma unroll
        for (int i = 0; i < 4; i++) {
            int row = bm + ri * 64 + ty * 4 + i;
            if (row >= M) continue;
#pragma unroll
            for (int ci = 0; ci < 2; ci++) {
                int col = bn + ci * 64 + tx * 4;
                float* cp = &C[(size_t)row * ncol + col];
                float4 v;
                v.x = acc[ri][ci][i][0];
                v.y = acc[ri][ci][i][1];
                v.z = acc[ri][ci][i][2];
                v.w = acc[ri][ci][i][3];
                if (MODE == 0) {
                    v.x += bias[col + 0];
                    v.y += bias[col + 1];
                    v.z += bias[col + 2];
                    v.w += bias[col + 3];
                } else {
                    float4 old = *(const float4*)cp;
                    v.x += old.x; v.y += old.y; v.z += old.z; v.w += old.w;
                    if (MODE == 2) {
                        v.x = fmaxf(v.x, 0.f); v.y = fmaxf(v.y, 0.f);
                        v.z = fmaxf(v.z, 0.f); v.w = fmaxf(v.w, 0.f);
                    }
                }
                *(float4*)cp = v;
            }
        }
    }
}

// ---------------------------------------------------------------------------
// Final linear [256->64] + fused log_softmax, tiled.
// Block: 256 threads, tile 128 rows x 64 cols. W staged in LDS in two
// 128-row halves (32KB each). Thread (tx=tid&15, ty=tid>>4) owns rows
// ty*8..ty*8+7, cols tx*4..tx*4+3. A row's 64 cols live in 16 consecutive
// lanes of one wave -> log_softmax via __shfl_xor(1,2,4,8).
// ---------------------------------------------------------------------------
__global__ __launch_bounds__(256) void k_final2(const float* __restrict__ h,
                                                const float* __restrict__ W,
                                                const float* __restrict__ bias,
                                                float* __restrict__ out, int M) {
    __shared__ __align__(16) float Ws[128][OUT_CH];  // 32 KB (one K-half)
    __shared__ __align__(16) float As[8][128];       // 4 KB
    const int tid = threadIdx.x;
    const int tx = tid & 15;
    const int ty = tid >> 4;
    const int bm = blockIdx.x * 128;
    const int arow = tid >> 1;       // 0..127
    const int acol = (tid & 1) * 4;  // 0 or 4
    const bool aval = (bm + arow) < M;
    float acc[8][4] = {};

    for (int half = 0; half < 2; half++) {
        // stage W rows [half*128, half*128+128) : 8192 floats, 1024/iter
        __syncthreads();
        for (int i = tid * 4; i < 128 * OUT_CH; i += 1024)
            *(float4*)((float*)Ws + i) = *(const float4*)(W + half * 128 * OUT_CH + i);
        for (int k0 = 0; k0 < 128; k0 += 8) {
            float4 av = make_float4(0.f, 0.f, 0.f, 0.f);
            if (aval)
                av = *(const float4*)(h + (size_t)(bm + arow) * HID + half * 128 + k0 + acol);
            __syncthreads();
            As[acol + 0][arow] = av.x;
            As[acol + 1][arow] = av.y;
            As[acol + 2][arow] = av.z;
            As[acol + 3][arow] = av.w;
            __syncthreads();
#pragma unroll
            for (int k = 0; k < 8; k++) {
                float a[8];
                *(float4*)&a[0] = *(const float4*)&As[k][ty * 8];
                *(float4*)&a[4] = *(const float4*)&As[k][ty * 8 + 4];
                float4 wv = *(const float4*)&Ws[k0 + k][tx * 4];
#pragma unroll
                for (int i = 0; i < 8; i++) {
                    acc[i][0] += a[i] * wv.x;
                    acc[i][1] += a[i] * wv.y;
                    acc[i][2] += a[i] * wv.z;
                    acc[i][3] += a[i] * wv.w;
                }
            }
        }
    }

    const float4 bv = *(const float4*)&bias[tx * 4];
#pragma unroll
    for (int i = 0; i < 8; i++) {
        int row = bm + ty * 8 + i;
        float v0 = acc[i][0] + bv.x;
        float v1 = acc[i][1] + bv.y;
        float v2 = acc[i][2] + bv.z;
        float v3 = acc[i][3] + bv.w;
        float m = fmaxf(fmaxf(v0, v1), fmaxf(v2, v3));
#pragma unroll
        for (int s = 1; s < 16; s <<= 1) m = fmaxf(m, __shfl_xor(m, s));
        float sum = expf(v0 - m) + expf(v1 - m) + expf(v2 - m) + expf(v3 - m);
#pragma unroll
        for (int s = 1; s < 16; s <<= 1) sum += __shfl_xor(sum, s);
        float lse = m + logf(sum);
        if (row < M) {
            float4 o;
            o.x = v0 - lse; o.y = v1 - lse; o.z = v2 - lse; o.w = v3 - lse;
            *(float4*)&out[(size_t)row * OUT_CH + tx * 4] = o;
        }
    }
}

// ---------------------------------------------------------------------------
extern "C" void kernel_launch(void* const* d_in, const int* in_sizes, int n_in,
                              void* d_out, int out_size, void* d_ws, size_t ws_size,
                              hipStream_t stream) {
    const float* x     = (const float*)d_in[0];
    const int*   eidx  = (const int*)d_in[1];
    const int*   etype = (const int*)d_in[2];
    const float* W1    = (const float*)d_in[3];
    const float* root1 = (const float*)d_in[4];
    const float* b1    = (const float*)d_in[5];
    const float* W2    = (const float*)d_in[6];
    const float* root2 = (const float*)d_in[7];
    const float* b2    = (const float*)d_in[8];
    const float* linW  = (const float*)d_in[9];
    const float* linb  = (const float*)d_in[10];
    float* out = (float*)d_out;
    const int* src = eidx;
    const int* dst = eidx + E_EDGES;

    char* ws = (char*)d_ws;
    size_t off = 0;
    auto alloc = [&](size_t bytes) {
        size_t o = off;
        off += (bytes + 255) & ~(size_t)255;
        return ws + o;
    };
    float* h1   = (float*)alloc((size_t)N_NODES * HID * 4);
    float* h2   = (float*)alloc((size_t)N_NODES * HID * 4);
    int* deg    = (int*)alloc((size_t)N_NODES * 4);
    int* cursor = (int*)alloc((size_t)N_NODES * 4);
    int* offs   = (int*)alloc((size_t)(N_NODES + 1) * 4);
    int* ekey   = (int*)alloc((size_t)E_EDGES * 4);
    float* aggS = (float*)(ws + off);  // rest of workspace
    const size_t availB = (ws_size > off) ? (ws_size - off) : 0;

    // Largest relation group whose stacked agg buffer fits (deterministic:
    // ws_size is fixed across calls). Round-3 bench proved ws_size >= base +
    // 51.2MB, so G >= 1 for both layers.
    auto pickG = [&](size_t perRelBytes) {
        for (int g = 8; g >= 2; g >>= 1)
            if ((size_t)g * perRelBytes <= availB) return g;
        return 1;
    };
    const int G1 = pickG((size_t)N_NODES * IN_CH * 4);
    const int G2 = pickG((size_t)N_NODES * HID * 4);

    hipMemsetAsync(deg, 0, (size_t)N_NODES * 4, stream);
    hipMemsetAsync(cursor, 0, (size_t)N_NODES * 4, stream);
    k_deg<<<(E_EDGES + 255) / 256, 256, 0, stream>>>(dst, deg);
    k_scan<<<1, 1024, 0, stream>>>(deg, offs);
    k_place<<<(E_EDGES + 255) / 256, 256, 0, stream>>>(src, dst, etype, offs, cursor, ekey);
    k_sort<<<(N_NODES + 255) / 256, 256, 0, stream>>>(offs, ekey);

    dim3 ggrid((N_NODES + 127) / 128, HID / 128);

    // Layer 1: h1 = relu(x@root1 + b1 + sum_g aggS_g @ W1_g)
    k_gemm<0><<<ggrid, 256, 0, stream>>>(x, root1, b1, h1, N_NODES, IN_CH, HID);
    for (int g0 = 0; g0 < NREL; g0 += G1) {
        k_agg_group<IN_CH><<<N_NODES, IN_CH, 0, stream>>>(x, offs, ekey, aggS, g0, G1);
        if (g0 + G1 >= NREL)
            k_gemm<2><<<ggrid, 256, 0, stream>>>(aggS, W1 + (size_t)g0 * IN_CH * HID,
                                                 nullptr, h1, N_NODES, G1 * IN_CH, HID);
        else
            k_gemm<1><<<ggrid, 256, 0, stream>>>(aggS, W1 + (size_t)g0 * IN_CH * HID,
                                                 nullptr, h1, N_NODES, G1 * IN_CH, HID);
    }

    // Layer 2: h2 = relu(h1@root2 + b2 + sum_g aggS_g @ W2_g)
    k_gemm<0><<<ggrid, 256, 0, stream>>>(h1, root2, b2, h2, N_NODES, HID, HID);
    for (int g0 = 0; g0 < NREL; g0 += G2) {
        k_agg_group<HID><<<N_NODES, HID, 0, stream>>>(h1, offs, ekey, aggS, g0, G2);
        if (g0 + G2 >= NREL)
            k_gemm<2><<<ggrid, 256, 0, stream>>>(aggS, W2 + (size_t)g0 * HID * HID,
                                                 nullptr, h2, N_NODES, G2 * HID, HID);
        else
            k_gemm<1><<<ggrid, 256, 0, stream>>>(aggS, W2 + (size_t)g0 * HID * HID,
                                                 nullptr, h2, N_NODES, G2 * HID, HID);
    }

    // Final linear + fused log_softmax
    k_final2<<<(N_NODES + 127) / 128, 256, 0, stream>>>(h2, linW, linb, out, N_NODES);
}

// Round 5
// 717.542 us; speedup vs baseline: 3.2932x; 2.6817x over previous
//
#include <hip/hip_runtime.h>
#include <hip/hip_bf16.h>

#define N_NODES 50000
#define E_EDGES 600000
#define IN_CH 128
#define HID 256
#define OUT_CH 64
#define NREL 8

typedef __attribute__((ext_vector_type(8))) short bf16x8;
typedef __attribute__((ext_vector_type(4))) float f32x4;

__device__ __forceinline__ float bf2f(unsigned short u) {
    union { unsigned int i; float f; } x; x.i = ((unsigned int)u) << 16; return x.f;
}
__device__ __forceinline__ unsigned short f2bf(float f) {
    __hip_bfloat16 b = __float2bfloat16(f);
    return *reinterpret_cast<unsigned short*>(&b);
}
__device__ __forceinline__ void gload_lds16(const void* g, void* l) {
    __builtin_amdgcn_global_load_lds(
        (const __attribute__((address_space(1))) unsigned int*)g,
        (__attribute__((address_space(3))) unsigned int*)l, 16, 0, 0);
}

// ---------------------------------------------------------------------------
// CSR construction (deterministic): histogram -> prefix scan -> placement ->
// per-node insertion sort by key (rel<<16 | src).
// ---------------------------------------------------------------------------
__global__ void k_deg(const int* __restrict__ dst, int* __restrict__ deg) {
    int e = blockIdx.x * blockDim.x + threadIdx.x;
    if (e < E_EDGES) atomicAdd(&deg[dst[e]], 1);
}

__global__ __launch_bounds__(1024) void k_scan(const int* __restrict__ deg,
                                               int* __restrict__ offs) {
    __shared__ int wsum[16];
    __shared__ int s_carry;
    const int lane = threadIdx.x & 63;
    const int wid = threadIdx.x >> 6;
    if (threadIdx.x == 0) s_carry = 0;
    __syncthreads();
    for (int base = 0; base < N_NODES; base += 1024) {
        int i = base + threadIdx.x;
        int v = (i < N_NODES) ? deg[i] : 0;
        int incl = v;
#pragma unroll
        for (int s = 1; s < 64; s <<= 1) {
            int t = __shfl_up(incl, s);
            if (lane >= s) incl += t;
        }
        if (lane == 63) wsum[wid] = incl;
        __syncthreads();
        if (wid == 0) {
            int wv = (lane < 16) ? wsum[lane] : 0;
            int wincl = wv;
#pragma unroll
            for (int s = 1; s < 16; s <<= 1) {
                int t = __shfl_up(wincl, s);
                if (lane >= s) wincl += t;
            }
            if (lane < 16) wsum[lane] = wincl - wv;
        }
        __syncthreads();
        int excl = s_carry + wsum[wid] + incl - v;
        if (i < N_NODES) offs[i] = excl;
        __syncthreads();
        if (threadIdx.x == 1023) s_carry = excl + v;
        __syncthreads();
    }
    if (threadIdx.x == 0) offs[N_NODES] = E_EDGES;
}

__global__ void k_place(const int* __restrict__ src, const int* __restrict__ dst,
                        const int* __restrict__ etype, const int* __restrict__ offs,
                        int* __restrict__ cursor, int* __restrict__ ekey) {
    int e = blockIdx.x * blockDim.x + threadIdx.x;
    if (e < E_EDGES) {
        int d = dst[e];
        int p = atomicAdd(&cursor[d], 1);
        ekey[offs[d] + p] = (etype[e] << 16) | src[e];
    }
}

__global__ void k_sort(const int* __restrict__ offs, int* __restrict__ ekey) {
    int i = blockIdx.x * blockDim.x + threadIdx.x;
    if (i >= N_NODES) return;
    int lo = offs[i], hi = offs[i + 1];
    for (int a = lo + 1; a < hi; a++) {
        int k = ekey[a];
        int b = a - 1;
        while (b >= lo && ekey[b] > k) { ekey[b + 1] = ekey[b]; b--; }
        ekey[b + 1] = k;
    }
}

// ---------------------------------------------------------------------------
// Conversions: x -> bf16; weights -> transposed bf16 Wt[c][k] so that both
// MFMA operands read contiguous-K fragments.
// ---------------------------------------------------------------------------
__global__ void k_cvt_x(const float* __restrict__ x, unsigned short* __restrict__ xb,
                        int n4) {
    int i = blockIdx.x * blockDim.x + threadIdx.x;
    if (i >= n4) return;
    float4 v = *(const float4*)&x[i * 4];
    short4 o;
    o.x = (short)f2bf(v.x); o.y = (short)f2bf(v.y);
    o.z = (short)f2bf(v.z); o.w = (short)f2bf(v.w);
    *(short4*)&xb[i * 4] = o;
}

// Wt1[c][k], k in [0,1152): k<128 -> root1[k][c]; else W1[(k-128)][c]
__global__ void k_wt1(const float* __restrict__ root1, const float* __restrict__ W1,
                      unsigned short* __restrict__ Wt) {
    int idx = blockIdx.x * blockDim.x + threadIdx.x;
    if (idx >= 256 * 1152) return;
    int c = idx / 1152, k = idx % 1152;
    float v = (k < IN_CH) ? root1[k * 256 + c] : W1[(size_t)(k - IN_CH) * 256 + c];
    Wt[idx] = f2bf(v);
}

// Wt2[c][k], k in [0,2304): k<256 -> root2[k][c]; else W2[(k-256)][c]
__global__ void k_wt2(const float* __restrict__ root2, const float* __restrict__ W2,
                      unsigned short* __restrict__ Wt) {
    int idx = blockIdx.x * blockDim.x + threadIdx.x;
    if (idx >= 256 * 2304) return;
    int c = idx / 2304, k = idx % 2304;
    float v = (k < HID) ? root2[k * 256 + c] : W2[(size_t)(k - HID) * 256 + c];
    Wt[idx] = f2bf(v);
}

// ---------------------------------------------------------------------------
// Grouped stacked aggregation (bf16 in / bf16 out, fp32 accumulate).
// agg[i, (r-rel0)*CH + c] = mean over rel-r in-edges of xin[src][c].
// ---------------------------------------------------------------------------
template <int CH>
__global__ void k_aggb(const unsigned short* __restrict__ xin,
                       const int* __restrict__ offs, const int* __restrict__ ekey,
                       unsigned short* __restrict__ agg, int rel0, int G, int ldout) {
    const int i = blockIdx.x;
    const int ch = threadIdx.x;
    unsigned short* row = agg + (size_t)i * ldout;
    for (int r = 0; r < G; r++) row[r * CH + ch] = 0;  // bf16 zero
    const int lo = offs[i], hi = offs[i + 1];
    const int rend = rel0 + G;
    float acc = 0.0f;
    int cnt = 0, cur = -1;
    for (int e = lo; e < hi; e++) {
        int k = ekey[e];
        int r = k >> 16;
        if (r < rel0) continue;
        if (r >= rend) break;
        if (r != cur) {
            if (cnt > 0) row[(cur - rel0) * CH + ch] = f2bf(acc / (float)cnt);
            cur = r; acc = 0.0f; cnt = 0;
        }
        cnt++;
        acc += bf2f(xin[(size_t)(k & 0xFFFF) * CH + ch]);
    }
    if (cnt > 0) row[(cur - rel0) * CH + ch] = f2bf(acc / (float)cnt);
}

// ---------------------------------------------------------------------------
// bf16 MFMA GEMM: C[M,256] = [Aroot | Aagg] @ Wt^T-slice, fp32 accumulate.
// Tile 128x128, BK=64, 256 thr = 4 waves, each wave 64x64 (4x4 frags of
// 16x16x32). LDS: A/B tiles [128 rows][8 slots of 16B], slot XOR-swizzled
// phys = slot ^ (row&7); staged via global_load_lds (linear dest,
// pre-swizzled per-lane source per m173), read conflict-free ds_read_b128.
// MODE 0: out = relu(A@B + bias) -> hb (bf16)
// MODE 1: accF = A@B + bias
// MODE 2: accF += A@B
// MODE 3: out = relu(accF + A@B) -> hb
// ---------------------------------------------------------------------------
template <int MODE>
__global__ __launch_bounds__(256) void k_mgemm(
    const unsigned short* __restrict__ Aroot, int rootK, int ldroot,
    const unsigned short* __restrict__ Aagg, int ldagg,
    const unsigned short* __restrict__ Wt, int ldWt, int kStart, int Ktot,
    const float* __restrict__ bias, float* __restrict__ accF,
    unsigned short* __restrict__ hbOut, int M) {
    __shared__ __align__(16) unsigned short Al[128 * 64];
    __shared__ __align__(16) unsigned short Bl[128 * 64];
    const int tid = threadIdx.x;
    const int wv = tid >> 6, ln = tid & 63;
    const int bm = blockIdx.x * 128;
    const int bn = blockIdx.y * 128;
    const int wr = (wv & 1) * 64;
    const int wc = (wv >> 1) * 64;
    const int lg = ln >> 4;
    const int lr = ln & 15;

    f32x4 acc[4][4];
#pragma unroll
    for (int m = 0; m < 4; m++)
#pragma unroll
        for (int n = 0; n < 4; n++) acc[m][n] = (f32x4){0.f, 0.f, 0.f, 0.f};

    // Pre-computed per-lane staging element-offsets (chunk q of this wave).
    int baseR[4], baseG[4], baseB[4];
#pragma unroll
    for (int q = 0; q < 4; q++) {
        int t = (wv * 4 + q) * 64 + ln;      // 16B slot index in tile
        int r = t >> 3, ps = t & 7;
        int slog = ps ^ (r & 7);
        int rg = bm + r; if (rg > M - 1) rg = M - 1;
        baseR[q] = (rootK > 0) ? (rg * ldroot + slog * 8) : 0;
        baseG[q] = rg * ldagg + slog * 8 - rootK;
        baseB[q] = (bn + r) * ldWt + kStart + slog * 8;
    }

    for (int k0 = 0; k0 < Ktot; k0 += 64) {
        __syncthreads();  // previous iteration's reads complete
        const bool inRoot = (k0 < rootK);
#pragma unroll
        for (int q = 0; q < 4; q++) {
            const unsigned short* sa =
                inRoot ? (Aroot + baseR[q] + k0) : (Aagg + baseG[q] + k0);
            gload_lds16(sa, &Al[(wv * 4 + q) * 512]);
        }
#pragma unroll
        for (int q = 0; q < 4; q++) {
            gload_lds16(Wt + baseB[q] + k0, &Bl[(wv * 4 + q) * 512]);
        }
        asm volatile("s_waitcnt vmcnt(0)" ::: "memory");
        __syncthreads();
#pragma unroll
        for (int kk = 0; kk < 2; kk++) {
            bf16x8 af[4], bfr[4];
#pragma unroll
            for (int m = 0; m < 4; m++) {
                int r = wr + 16 * m + lr;
                int ph = (kk * 4 + lg) ^ (r & 7);
                af[m] = *(const bf16x8*)&Al[r * 64 + ph * 8];
            }
#pragma unroll
            for (int n = 0; n < 4; n++) {
                int c = wc + 16 * n + lr;
                int ph = (kk * 4 + lg) ^ (c & 7);
                bfr[n] = *(const bf16x8*)&Bl[c * 64 + ph * 8];
            }
#pragma unroll
            for (int m = 0; m < 4; m++)
#pragma unroll
                for (int n = 0; n < 4; n++)
                    acc[m][n] = __builtin_amdgcn_mfma_f32_16x16x32_bf16(
                        af[m], bfr[n], acc[m][n], 0, 0, 0);
        }
    }

    // Epilogue. C/D: col = lane&15, row = (lane>>4)*4 + reg  [m89/m91]
#pragma unroll
    for (int m = 0; m < 4; m++) {
#pragma unroll
        for (int reg = 0; reg < 4; reg++) {
            int row = bm + wr + 16 * m + lg * 4 + reg;
            if (row >= M) continue;
#pragma unroll
            for (int n = 0; n < 4; n++) {
                int col = bn + wc + 16 * n + lr;
                float v = acc[m][n][reg];
                size_t idx = (size_t)row * 256 + col;
                if (MODE == 0) {
                    v += bias[col];
                    hbOut[idx] = f2bf(fmaxf(v, 0.f));
                } else if (MODE == 1) {
                    accF[idx] = v + bias[col];
                } else if (MODE == 2) {
                    accF[idx] += v;
                } else {
                    v += accF[idx];
                    hbOut[idx] = f2bf(fmaxf(v, 0.f));
                }
            }
        }
    }
}

// ---------------------------------------------------------------------------
// Final linear [256->64] (bf16 h in, fp32 W) + fused log_softmax.
// ---------------------------------------------------------------------------
__global__ __launch_bounds__(256) void k_final2(const unsigned short* __restrict__ h,
                                                const float* __restrict__ W,
                                                const float* __restrict__ bias,
                                                float* __restrict__ out, int M) {
    __shared__ __align__(16) float Ws[128][OUT_CH];
    __shared__ __align__(16) float As[8][128];
    const int tid = threadIdx.x;
    const int tx = tid & 15;
    const int ty = tid >> 4;
    const int bm = blockIdx.x * 128;
    const int arow = tid >> 1;
    const int acol = (tid & 1) * 4;
    const bool aval = (bm + arow) < M;
    float acc[8][4] = {};

    for (int half = 0; half < 2; half++) {
        __syncthreads();
        for (int i = tid * 4; i < 128 * OUT_CH; i += 1024)
            *(float4*)((float*)Ws + i) = *(const float4*)(W + half * 128 * OUT_CH + i);
        for (int k0 = 0; k0 < 128; k0 += 8) {
            float4 av = make_float4(0.f, 0.f, 0.f, 0.f);
            if (aval) {
                short4 hv = *(const short4*)&h[(size_t)(bm + arow) * HID + half * 128 + k0 + acol];
                av.x = bf2f((unsigned short)hv.x);
                av.y = bf2f((unsigned short)hv.y);
                av.z = bf2f((unsigned short)hv.z);
                av.w = bf2f((unsigned short)hv.w);
            }
            __syncthreads();
            As[acol + 0][arow] = av.x;
            As[acol + 1][arow] = av.y;
            As[acol + 2][arow] = av.z;
            As[acol + 3][arow] = av.w;
            __syncthreads();
#pragma unroll
            for (int k = 0; k < 8; k++) {
                float a[8];
                *(float4*)&a[0] = *(const float4*)&As[k][ty * 8];
                *(float4*)&a[4] = *(const float4*)&As[k][ty * 8 + 4];
                float4 wv = *(const float4*)&Ws[k0 + k][tx * 4];
#pragma unroll
                for (int i = 0; i < 8; i++) {
                    acc[i][0] += a[i] * wv.x;
                    acc[i][1] += a[i] * wv.y;
                    acc[i][2] += a[i] * wv.z;
                    acc[i][3] += a[i] * wv.w;
                }
            }
        }
    }

    const float4 bv = *(const float4*)&bias[tx * 4];
#pragma unroll
    for (int i = 0; i < 8; i++) {
        int row = bm + ty * 8 + i;
        float v0 = acc[i][0] + bv.x;
        float v1 = acc[i][1] + bv.y;
        float v2 = acc[i][2] + bv.z;
        float v3 = acc[i][3] + bv.w;
        float m = fmaxf(fmaxf(v0, v1), fmaxf(v2, v3));
#pragma unroll
        for (int s = 1; s < 16; s <<= 1) m = fmaxf(m, __shfl_xor(m, s));
        float sum = expf(v0 - m) + expf(v1 - m) + expf(v2 - m) + expf(v3 - m);
#pragma unroll
        for (int s = 1; s < 16; s <<= 1) sum += __shfl_xor(sum, s);
        float lse = m + logf(sum);
        if (row < M) {
            float4 o;
            o.x = v0 - lse; o.y = v1 - lse; o.z = v2 - lse; o.w = v3 - lse;
            *(float4*)&out[(size_t)row * OUT_CH + tx * 4] = o;
        }
    }
}

// ---------------------------------------------------------------------------
extern "C" void kernel_launch(void* const* d_in, const int* in_sizes, int n_in,
                              void* d_out, int out_size, void* d_ws, size_t ws_size,
                              hipStream_t stream) {
    const float* x     = (const float*)d_in[0];
    const int*   eidx  = (const int*)d_in[1];
    const int*   etype = (const int*)d_in[2];
    const float* W1    = (const float*)d_in[3];
    const float* root1 = (const float*)d_in[4];
    const float* b1    = (const float*)d_in[5];
    const float* W2    = (const float*)d_in[6];
    const float* root2 = (const float*)d_in[7];
    const float* b2    = (const float*)d_in[8];
    const float* linW  = (const float*)d_in[9];
    const float* linb  = (const float*)d_in[10];
    float* out = (float*)d_out;
    const int* srcI = eidx;
    const int* dstI = eidx + E_EDGES;

    char* ws = (char*)d_ws;
    size_t off = 0;
    auto alloc = [&](size_t bytes) {
        size_t o = off;
        off += (bytes + 255) & ~(size_t)255;
        return ws + o;
    };
    unsigned short* xb  = (unsigned short*)alloc((size_t)N_NODES * IN_CH * 2);
    unsigned short* hb1 = (unsigned short*)alloc((size_t)N_NODES * HID * 2);
    unsigned short* hb2 = (unsigned short*)alloc((size_t)N_NODES * HID * 2);
    unsigned short* Wt1 = (unsigned short*)alloc((size_t)256 * 1152 * 2);
    unsigned short* Wt2 = (unsigned short*)alloc((size_t)256 * 2304 * 2);
    int* deg    = (int*)alloc((size_t)N_NODES * 4);
    int* cursor = (int*)alloc((size_t)N_NODES * 4);
    int* offs   = (int*)alloc((size_t)(N_NODES + 1) * 4);
    int* ekey   = (int*)alloc((size_t)E_EDGES * 4);
    char* bigR  = ws + off;
    const size_t S = (ws_size > off) ? (ws_size - off) : 0;

    // L1: G=8 single fused GEMM (needs 102.4MB agg; S >= ~138MB proven).
    unsigned short* aggL1 = (unsigned short*)bigR;
    // L2 adaptive: G2=8 (no accF) / 4 / 2.
    const size_t MB = 1024ull * 1024ull;
    int G2; float* accF; unsigned short* aggL2;
    if (S >= (size_t)(204.9 * MB)) {
        G2 = 8; accF = nullptr; aggL2 = (unsigned short*)bigR;
    } else if (S >= (size_t)(153.7 * MB)) {
        G2 = 4; accF = (float*)bigR; aggL2 = (unsigned short*)(bigR + (size_t)N_NODES * HID * 4);
    } else {
        G2 = 2; accF = (float*)bigR; aggL2 = (unsigned short*)(bigR + (size_t)N_NODES * HID * 4);
    }

    // conversions + CSR
    k_cvt_x<<<(N_NODES * IN_CH / 4 + 255) / 256, 256, 0, stream>>>(x, xb, N_NODES * IN_CH / 4);
    k_wt1<<<(256 * 1152 + 255) / 256, 256, 0, stream>>>(root1, W1, Wt1);
    k_wt2<<<(256 * 2304 + 255) / 256, 256, 0, stream>>>(root2, W2, Wt2);
    hipMemsetAsync(deg, 0, (size_t)N_NODES * 4, stream);
    hipMemsetAsync(cursor, 0, (size_t)N_NODES * 4, stream);
    k_deg<<<(E_EDGES + 255) / 256, 256, 0, stream>>>(dstI, deg);
    k_scan<<<1, 1024, 0, stream>>>(deg, offs);
    k_place<<<(E_EDGES + 255) / 256, 256, 0, stream>>>(srcI, dstI, etype, offs, cursor, ekey);
    k_sort<<<(N_NODES + 255) / 256, 256, 0, stream>>>(offs, ekey);

    dim3 ggrid((N_NODES + 127) / 128, 2);

    // ---- Layer 1: one fused GEMM, K = 128 + 8*128 = 1152 ----
    k_aggb<IN_CH><<<N_NODES, IN_CH, 0, stream>>>(xb, offs, ekey, aggL1, 0, 8, 8 * IN_CH);
    k_mgemm<0><<<ggrid, 256, 0, stream>>>(xb, IN_CH, IN_CH, aggL1, 8 * IN_CH,
                                          Wt1, 1152, 0, 1152, b1, nullptr, hb1, N_NODES);

    // ---- Layer 2 ----
    if (G2 == 8) {
        k_aggb<HID><<<N_NODES, HID, 0, stream>>>(hb1, offs, ekey, aggL2, 0, 8, 8 * HID);
        k_mgemm<0><<<ggrid, 256, 0, stream>>>(hb1, HID, HID, aggL2, 8 * HID,
                                              Wt2, 2304, 0, 2304, b2, nullptr, hb2, N_NODES);
    } else {
        const int ldA = G2 * HID;
        // first group: fused root, MODE1
        k_aggb<HID><<<N_NODES, HID, 0, stream>>>(hb1, offs, ekey, aggL2, 0, G2, ldA);
        k_mgemm<1><<<ggrid, 256, 0, stream>>>(hb1, HID, HID, aggL2, ldA,
                                              Wt2, 2304, 0, HID + G2 * HID, b2, accF,
                                              nullptr, N_NODES);
        for (int g0 = G2; g0 < NREL; g0 += G2) {
            k_aggb<HID><<<N_NODES, HID, 0, stream>>>(hb1, offs, ekey, aggL2, g0, G2, ldA);
            int kS = HID + g0 * HID;
            if (g0 + G2 >= NREL)
                k_mgemm<3><<<ggrid, 256, 0, stream>>>(nullptr, 0, 0, aggL2, ldA,
                                                      Wt2, 2304, kS, G2 * HID, nullptr,
                                                      accF, hb2, N_NODES);
            else
                k_mgemm<2><<<ggrid, 256, 0, stream>>>(nullptr, 0, 0, aggL2, ldA,
                                                      Wt2, 2304, kS, G2 * HID, nullptr,
                                                      accF, nullptr, N_NODES);
        }
    }

    // ---- Final linear + log_softmax ----
    k_final2<<<(N_NODES + 127) / 128, 256, 0, stream>>>(hb2, linW, linb, out, N_NODES);
}

// Round 6
// 582.964 us; speedup vs baseline: 4.0535x; 1.2309x over previous
//
#include <hip/hip_runtime.h>
#include <hip/hip_bf16.h>

#define N_NODES 50000
#define E_EDGES 600000
#define IN_CH 128
#define HID 256
#define OUT_CH 64
#define NREL 8
#define CHUNK 25000

typedef __attribute__((ext_vector_type(8))) short bf16x8;
typedef __attribute__((ext_vector_type(4))) float f32x4;

__device__ __forceinline__ float bf2f(unsigned short u) {
    union { unsigned int i; float f; } x; x.i = ((unsigned int)u) << 16; return x.f;
}
__device__ __forceinline__ unsigned short f2bf(float f) {
    __hip_bfloat16 b = __float2bfloat16(f);
    return *reinterpret_cast<unsigned short*>(&b);
}
__device__ __forceinline__ void gload_lds16(const void* g, void* l) {
    __builtin_amdgcn_global_load_lds(
        (const __attribute__((address_space(1))) unsigned int*)g,
        (__attribute__((address_space(3))) unsigned int*)l, 16, 0, 0);
}

// ---------------------------------------------------------------------------
// CSR construction (deterministic): histogram -> prefix scan -> placement ->
// per-node insertion sort by key (rel<<16 | src) -> per-relation segment
// bounds relOffs[N][9].
// ---------------------------------------------------------------------------
__global__ void k_deg(const int* __restrict__ dst, int* __restrict__ deg) {
    int e = blockIdx.x * blockDim.x + threadIdx.x;
    if (e < E_EDGES) atomicAdd(&deg[dst[e]], 1);
}

__global__ __launch_bounds__(1024) void k_scan(const int* __restrict__ deg,
                                               int* __restrict__ offs) {
    __shared__ int wsum[16];
    __shared__ int s_carry;
    const int lane = threadIdx.x & 63;
    const int wid = threadIdx.x >> 6;
    if (threadIdx.x == 0) s_carry = 0;
    __syncthreads();
    for (int base = 0; base < N_NODES; base += 1024) {
        int i = base + threadIdx.x;
        int v = (i < N_NODES) ? deg[i] : 0;
        int incl = v;
#pragma unroll
        for (int s = 1; s < 64; s <<= 1) {
            int t = __shfl_up(incl, s);
            if (lane >= s) incl += t;
        }
        if (lane == 63) wsum[wid] = incl;
        __syncthreads();
        if (wid == 0) {
            int wv = (lane < 16) ? wsum[lane] : 0;
            int wincl = wv;
#pragma unroll
            for (int s = 1; s < 16; s <<= 1) {
                int t = __shfl_up(wincl, s);
                if (lane >= s) wincl += t;
            }
            if (lane < 16) wsum[lane] = wincl - wv;
        }
        __syncthreads();
        int excl = s_carry + wsum[wid] + incl - v;
        if (i < N_NODES) offs[i] = excl;
        __syncthreads();
        if (threadIdx.x == 1023) s_carry = excl + v;
        __syncthreads();
    }
    if (threadIdx.x == 0) offs[N_NODES] = E_EDGES;
}

__global__ void k_place(const int* __restrict__ src, const int* __restrict__ dst,
                        const int* __restrict__ etype, const int* __restrict__ offs,
                        int* __restrict__ cursor, int* __restrict__ ekey) {
    int e = blockIdx.x * blockDim.x + threadIdx.x;
    if (e < E_EDGES) {
        int d = dst[e];
        int p = atomicAdd(&cursor[d], 1);
        ekey[offs[d] + p] = (etype[e] << 16) | src[e];
    }
}

__global__ void k_sort(const int* __restrict__ offs, int* __restrict__ ekey) {
    int i = blockIdx.x * blockDim.x + threadIdx.x;
    if (i >= N_NODES) return;
    int lo = offs[i], hi = offs[i + 1];
    for (int a = lo + 1; a < hi; a++) {
        int k = ekey[a];
        int b = a - 1;
        while (b >= lo && ekey[b] > k) { ekey[b + 1] = ekey[b]; b--; }
        ekey[b + 1] = k;
    }
}

__global__ void k_segs(const int* __restrict__ offs, const int* __restrict__ ekey,
                       int* __restrict__ relOffs) {
    int i = blockIdx.x * blockDim.x + threadIdx.x;
    if (i >= N_NODES) return;
    int lo = offs[i], hi = offs[i + 1];
    int p = lo;
    relOffs[i * 9] = lo;
#pragma unroll
    for (int r = 0; r < NREL; r++) {
        while (p < hi && (ekey[p] >> 16) == r) p++;
        relOffs[i * 9 + r + 1] = p;
    }
}

// ---------------------------------------------------------------------------
// Conversions: x -> bf16; weights -> transposed bf16 Wt[c][k] (root fused as
// leading K block).
// ---------------------------------------------------------------------------
__global__ void k_cvt_x(const float* __restrict__ x, unsigned short* __restrict__ xb,
                        int n4) {
    int i = blockIdx.x * blockDim.x + threadIdx.x;
    if (i >= n4) return;
    float4 v = *(const float4*)&x[i * 4];
    short4 o;
    o.x = (short)f2bf(v.x); o.y = (short)f2bf(v.y);
    o.z = (short)f2bf(v.z); o.w = (short)f2bf(v.w);
    *(short4*)&xb[i * 4] = o;
}

__global__ void k_wt1(const float* __restrict__ root1, const float* __restrict__ W1,
                      unsigned short* __restrict__ Wt) {
    int idx = blockIdx.x * blockDim.x + threadIdx.x;
    if (idx >= 256 * 1152) return;
    int c = idx / 1152, k = idx % 1152;
    float v = (k < IN_CH) ? root1[k * 256 + c] : W1[(size_t)(k - IN_CH) * 256 + c];
    Wt[idx] = f2bf(v);
}

__global__ void k_wt2(const float* __restrict__ root2, const float* __restrict__ W2,
                      unsigned short* __restrict__ Wt) {
    int idx = blockIdx.x * blockDim.x + threadIdx.x;
    if (idx >= 256 * 2304) return;
    int c = idx / 2304, k = idx % 2304;
    float v = (k < HID) ? root2[k * 256 + c] : W2[(size_t)(k - HID) * 256 + c];
    Wt[idx] = f2bf(v);
}

// ---------------------------------------------------------------------------
// Full-relation mean aggregation, one wave per node, lane owns CH/64
// channels. Branch-free per-relation segments from relOffs. One write per
// (node, rel, ch) slot — zeros for empty segments (buffer is poisoned).
// ---------------------------------------------------------------------------
template <int CH>
__global__ __launch_bounds__(256) void k_agg8(const unsigned short* __restrict__ xin,
                                              const int* __restrict__ relOffs,
                                              const int* __restrict__ ekey,
                                              unsigned short* __restrict__ agg,
                                              int base, int count) {
    const int w = threadIdx.x >> 6;
    const int t = threadIdx.x & 63;
    const int rel_node = blockIdx.x * 4 + w;
    if (rel_node >= count) return;
    const int node = base + rel_node;
    constexpr int VPT = CH / 64;  // 4 (CH=256) or 2 (CH=128)
    const unsigned short* xcol = xin + t * VPT;
    unsigned short* orow = agg + (size_t)rel_node * (NREL * CH) + t * VPT;
    const int* ro = relOffs + node * 9;
#pragma unroll
    for (int r = 0; r < NREL; r++) {
        const int s = ro[r], e = ro[r + 1];
        float a0 = 0.f, a1 = 0.f, a2 = 0.f, a3 = 0.f;
        for (int ee = s; ee < e; ee++) {
            int src = ekey[ee] & 0xFFFF;
            if (VPT == 4) {
                short4 v = *(const short4*)(xcol + (size_t)src * CH);
                a0 += bf2f((unsigned short)v.x);
                a1 += bf2f((unsigned short)v.y);
                a2 += bf2f((unsigned short)v.z);
                a3 += bf2f((unsigned short)v.w);
            } else {
                short2 v = *(const short2*)(xcol + (size_t)src * CH);
                a0 += bf2f((unsigned short)v.x);
                a1 += bf2f((unsigned short)v.y);
            }
        }
        const float inv = (e > s) ? 1.0f / (float)(e - s) : 0.0f;
        if (VPT == 4) {
            short4 o;
            o.x = (short)f2bf(a0 * inv);
            o.y = (short)f2bf(a1 * inv);
            o.z = (short)f2bf(a2 * inv);
            o.w = (short)f2bf(a3 * inv);
            *(short4*)(orow + (size_t)r * CH) = o;
        } else {
            short2 o;
            o.x = (short)f2bf(a0 * inv);
            o.y = (short)f2bf(a1 * inv);
            *(short2*)(orow + (size_t)r * CH) = o;
        }
    }
}

// ---------------------------------------------------------------------------
// bf16 MFMA GEMM: hbOut[M,256] = relu([Aroot | Aagg] @ Wt-slice + bias), bf16
// out, fp32 accumulate. Tile 128x128, BK=64, 4 waves. XOR-swizzled LDS
// (phys slot = slot ^ (row&7)), staged via global_load_lds with pre-swizzled
// per-lane global source (m173/m201), read via conflict-free ds_read_b128.
// ---------------------------------------------------------------------------
__global__ __launch_bounds__(256) void k_mgemm(
    const unsigned short* __restrict__ Aroot, int rootK, int ldroot,
    const unsigned short* __restrict__ Aagg, int ldagg,
    const unsigned short* __restrict__ Wt, int ldWt, int Ktot,
    const float* __restrict__ bias, unsigned short* __restrict__ hbOut, int M) {
    __shared__ __align__(16) unsigned short Al[128 * 64];
    __shared__ __align__(16) unsigned short Bl[128 * 64];
    const int tid = threadIdx.x;
    const int wv = tid >> 6, ln = tid & 63;
    const int bm = blockIdx.x * 128;
    const int bn = blockIdx.y * 128;
    const int wr = (wv & 1) * 64;
    const int wc = (wv >> 1) * 64;
    const int lg = ln >> 4;
    const int lr = ln & 15;

    f32x4 acc[4][4];
#pragma unroll
    for (int m = 0; m < 4; m++)
#pragma unroll
        for (int n = 0; n < 4; n++) acc[m][n] = (f32x4){0.f, 0.f, 0.f, 0.f};

    int baseR[4], baseG[4], baseB[4];
#pragma unroll
    for (int q = 0; q < 4; q++) {
        int t = (wv * 4 + q) * 64 + ln;
        int r = t >> 3, ps = t & 7;
        int slog = ps ^ (r & 7);
        int rg = bm + r; if (rg > M - 1) rg = M - 1;
        baseR[q] = (rootK > 0) ? (rg * ldroot + slog * 8) : 0;
        baseG[q] = rg * ldagg + slog * 8 - rootK;
        baseB[q] = (bn + r) * ldWt + slog * 8;
    }

    for (int k0 = 0; k0 < Ktot; k0 += 64) {
        __syncthreads();
        const bool inRoot = (k0 < rootK);
#pragma unroll
        for (int q = 0; q < 4; q++) {
            const unsigned short* sa =
                inRoot ? (Aroot + baseR[q] + k0) : (Aagg + baseG[q] + k0);
            gload_lds16(sa, &Al[(wv * 4 + q) * 512]);
        }
#pragma unroll
        for (int q = 0; q < 4; q++) {
            gload_lds16(Wt + baseB[q] + k0, &Bl[(wv * 4 + q) * 512]);
        }
        asm volatile("s_waitcnt vmcnt(0)" ::: "memory");
        __syncthreads();
#pragma unroll
        for (int kk = 0; kk < 2; kk++) {
            bf16x8 af[4], bfr[4];
#pragma unroll
            for (int m = 0; m < 4; m++) {
                int r = wr + 16 * m + lr;
                int ph = (kk * 4 + lg) ^ (r & 7);
                af[m] = *(const bf16x8*)&Al[r * 64 + ph * 8];
            }
#pragma unroll
            for (int n = 0; n < 4; n++) {
                int c = wc + 16 * n + lr;
                int ph = (kk * 4 + lg) ^ (c & 7);
                bfr[n] = *(const bf16x8*)&Bl[c * 64 + ph * 8];
            }
#pragma unroll
            for (int m = 0; m < 4; m++)
#pragma unroll
                for (int n = 0; n < 4; n++)
                    acc[m][n] = __builtin_amdgcn_mfma_f32_16x16x32_bf16(
                        af[m], bfr[n], acc[m][n], 0, 0, 0);
        }
    }

    // C/D: col = lane&15, row = (lane>>4)*4 + reg  [m89/m91]
#pragma unroll
    for (int m = 0; m < 4; m++) {
#pragma unroll
        for (int reg = 0; reg < 4; reg++) {
            int row = bm + wr + 16 * m + lg * 4 + reg;
            if (row >= M) continue;
#pragma unroll
            for (int n = 0; n < 4; n++) {
                int col = bn + wc + 16 * n + lr;
                float v = acc[m][n][reg] + bias[col];
                hbOut[(size_t)row * 256 + col] = f2bf(fmaxf(v, 0.f));
            }
        }
    }
}

// ---------------------------------------------------------------------------
// Final linear [256->64] (bf16 h in, fp32 W) + fused log_softmax.
// ---------------------------------------------------------------------------
__global__ __launch_bounds__(256) void k_final2(const unsigned short* __restrict__ h,
                                                const float* __restrict__ W,
                                                const float* __restrict__ bias,
                                                float* __restrict__ out, int M) {
    __shared__ __align__(16) float Ws[128][OUT_CH];
    __shared__ __align__(16) float As[8][128];
    const int tid = threadIdx.x;
    const int tx = tid & 15;
    const int ty = tid >> 4;
    const int bm = blockIdx.x * 128;
    const int arow = tid >> 1;
    const int acol = (tid & 1) * 4;
    const bool aval = (bm + arow) < M;
    float acc[8][4] = {};

    for (int half = 0; half < 2; half++) {
        __syncthreads();
        for (int i = tid * 4; i < 128 * OUT_CH; i += 1024)
            *(float4*)((float*)Ws + i) = *(const float4*)(W + half * 128 * OUT_CH + i);
        for (int k0 = 0; k0 < 128; k0 += 8) {
            float4 av = make_float4(0.f, 0.f, 0.f, 0.f);
            if (aval) {
                short4 hv = *(const short4*)&h[(size_t)(bm + arow) * HID + half * 128 + k0 + acol];
                av.x = bf2f((unsigned short)hv.x);
                av.y = bf2f((unsigned short)hv.y);
                av.z = bf2f((unsigned short)hv.z);
                av.w = bf2f((unsigned short)hv.w);
            }
            __syncthreads();
            As[acol + 0][arow] = av.x;
            As[acol + 1][arow] = av.y;
            As[acol + 2][arow] = av.z;
            As[acol + 3][arow] = av.w;
            __syncthreads();
#pragma unroll
            for (int k = 0; k < 8; k++) {
                float a[8];
                *(float4*)&a[0] = *(const float4*)&As[k][ty * 8];
                *(float4*)&a[4] = *(const float4*)&As[k][ty * 8 + 4];
                float4 wv = *(const float4*)&Ws[k0 + k][tx * 4];
#pragma unroll
                for (int i = 0; i < 8; i++) {
                    acc[i][0] += a[i] * wv.x;
                    acc[i][1] += a[i] * wv.y;
                    acc[i][2] += a[i] * wv.z;
                    acc[i][3] += a[i] * wv.w;
                }
            }
        }
    }

    const float4 bv = *(const float4*)&bias[tx * 4];
#pragma unroll
    for (int i = 0; i < 8; i++) {
        int row = bm + ty * 8 + i;
        float v0 = acc[i][0] + bv.x;
        float v1 = acc[i][1] + bv.y;
        float v2 = acc[i][2] + bv.z;
        float v3 = acc[i][3] + bv.w;
        float m = fmaxf(fmaxf(v0, v1), fmaxf(v2, v3));
#pragma unroll
        for (int s = 1; s < 16; s <<= 1) m = fmaxf(m, __shfl_xor(m, s));
        float sum = expf(v0 - m) + expf(v1 - m) + expf(v2 - m) + expf(v3 - m);
#pragma unroll
        for (int s = 1; s < 16; s <<= 1) sum += __shfl_xor(sum, s);
        float lse = m + logf(sum);
        if (row < M) {
            float4 o;
            o.x = v0 - lse; o.y = v1 - lse; o.z = v2 - lse; o.w = v3 - lse;
            *(float4*)&out[(size_t)row * OUT_CH + tx * 4] = o;
        }
    }
}

// ---------------------------------------------------------------------------
extern "C" void kernel_launch(void* const* d_in, const int* in_sizes, int n_in,
                              void* d_out, int out_size, void* d_ws, size_t ws_size,
                              hipStream_t stream) {
    const float* x     = (const float*)d_in[0];
    const int*   eidx  = (const int*)d_in[1];
    const int*   etype = (const int*)d_in[2];
    const float* W1    = (const float*)d_in[3];
    const float* root1 = (const float*)d_in[4];
    const float* b1    = (const float*)d_in[5];
    const float* W2    = (const float*)d_in[6];
    const float* root2 = (const float*)d_in[7];
    const float* b2    = (const float*)d_in[8];
    const float* linW  = (const float*)d_in[9];
    const float* linb  = (const float*)d_in[10];
    float* out = (float*)d_out;
    const int* srcI = eidx;
    const int* dstI = eidx + E_EDGES;

    char* ws = (char*)d_ws;
    size_t off = 0;
    auto alloc = [&](size_t bytes) {
        size_t o = off;
        off += (bytes + 255) & ~(size_t)255;
        return ws + o;
    };
    unsigned short* xb   = (unsigned short*)alloc((size_t)N_NODES * IN_CH * 2);
    unsigned short* hb1  = (unsigned short*)alloc((size_t)N_NODES * HID * 2);
    unsigned short* hb2  = (unsigned short*)alloc((size_t)N_NODES * HID * 2);
    unsigned short* Wt1  = (unsigned short*)alloc((size_t)256 * 1152 * 2);
    unsigned short* Wt2  = (unsigned short*)alloc((size_t)256 * 2304 * 2);
    int* deg     = (int*)alloc((size_t)N_NODES * 4);
    int* cursor  = (int*)alloc((size_t)N_NODES * 4);
    int* offs    = (int*)alloc((size_t)(N_NODES + 1) * 4);
    int* ekey    = (int*)alloc((size_t)E_EDGES * 4);
    int* relOffs = (int*)alloc((size_t)N_NODES * 9 * 4);
    // agg buffer: max(50000 x 8*128, 25000 x 8*256) bf16 = 102.4 MB
    unsigned short* agg = (unsigned short*)alloc((size_t)N_NODES * NREL * IN_CH * 2);

    // conversions + CSR
    k_cvt_x<<<(N_NODES * IN_CH / 4 + 255) / 256, 256, 0, stream>>>(x, xb, N_NODES * IN_CH / 4);
    k_wt1<<<(256 * 1152 + 255) / 256, 256, 0, stream>>>(root1, W1, Wt1);
    k_wt2<<<(256 * 2304 + 255) / 256, 256, 0, stream>>>(root2, W2, Wt2);
    hipMemsetAsync(deg, 0, (size_t)N_NODES * 4, stream);
    hipMemsetAsync(cursor, 0, (size_t)N_NODES * 4, stream);
    k_deg<<<(E_EDGES + 255) / 256, 256, 0, stream>>>(dstI, deg);
    k_scan<<<1, 1024, 0, stream>>>(deg, offs);
    k_place<<<(E_EDGES + 255) / 256, 256, 0, stream>>>(srcI, dstI, etype, offs, cursor, ekey);
    k_sort<<<(N_NODES + 255) / 256, 256, 0, stream>>>(offs, ekey);
    k_segs<<<(N_NODES + 255) / 256, 256, 0, stream>>>(offs, ekey, relOffs);

    // ---- Layer 1: agg (one pass) + one fused GEMM, K = 128 + 1024 ----
    k_agg8<IN_CH><<<(N_NODES + 3) / 4, 256, 0, stream>>>(xb, relOffs, ekey, agg, 0, N_NODES);
    {
        dim3 g((N_NODES + 127) / 128, 2);
        k_mgemm<<<g, 256, 0, stream>>>(xb, IN_CH, IN_CH, agg, NREL * IN_CH,
                                       Wt1, 1152, 1152, b1, hb1, N_NODES);
    }

    // ---- Layer 2: two M-chunks, each agg (one pass) + one fused GEMM,
    //      K = 256 + 2048 ----
    for (int c = 0; c < 2; c++) {
        const int base = c * CHUNK;
        const int cnt = (base + CHUNK <= N_NODES) ? CHUNK : (N_NODES - base);
        k_agg8<HID><<<(cnt + 3) / 4, 256, 0, stream>>>(hb1, relOffs, ekey, agg, base, cnt);
        dim3 g((cnt + 127) / 128, 2);
        k_mgemm<<<g, 256, 0, stream>>>(hb1 + (size_t)base * HID, HID, HID,
                                       agg, NREL * HID, Wt2, 2304, 2304, b2,
                                       hb2 + (size_t)base * HID, cnt);
    }

    // ---- Final linear + log_softmax ----
    k_final2<<<(N_NODES + 127) / 128, 256, 0, stream>>>(hb2, linW, linb, out, N_NODES);
}

// Round 7
// 539.922 us; speedup vs baseline: 4.3766x; 1.0797x over previous
//
#include <hip/hip_runtime.h>
#include <hip/hip_bf16.h>

#define N_NODES 50000
#define E_EDGES 600000
#define IN_CH 128
#define HID 256
#define OUT_CH 64
#define NREL 8
#define CHUNK 25000

typedef __attribute__((ext_vector_type(8))) short bf16x8;
typedef __attribute__((ext_vector_type(4))) float f32x4;

__device__ __forceinline__ float bf2f(unsigned short u) {
    union { unsigned int i; float f; } x; x.i = ((unsigned int)u) << 16; return x.f;
}
__device__ __forceinline__ unsigned short f2bf(float f) {
    __hip_bfloat16 b = __float2bfloat16(f);
    return *reinterpret_cast<unsigned short*>(&b);
}
__device__ __forceinline__ void gload_lds16(const void* g, void* l) {
    __builtin_amdgcn_global_load_lds(
        (const __attribute__((address_space(1))) unsigned int*)g,
        (__attribute__((address_space(3))) unsigned int*)l, 16, 0, 0);
}

// ---------------------------------------------------------------------------
// CSR construction (deterministic): histogram -> prefix scan -> placement ->
// per-node insertion sort by key (rel<<16 | src) -> per-relation segment
// bounds relOffs[N][9].
// ---------------------------------------------------------------------------
__global__ void k_deg(const int* __restrict__ dst, int* __restrict__ deg) {
    int e = blockIdx.x * blockDim.x + threadIdx.x;
    if (e < E_EDGES) atomicAdd(&deg[dst[e]], 1);
}

__global__ __launch_bounds__(1024) void k_scan(const int* __restrict__ deg,
                                               int* __restrict__ offs) {
    __shared__ int wsum[16];
    __shared__ int s_carry;
    const int lane = threadIdx.x & 63;
    const int wid = threadIdx.x >> 6;
    if (threadIdx.x == 0) s_carry = 0;
    __syncthreads();
    for (int base = 0; base < N_NODES; base += 1024) {
        int i = base + threadIdx.x;
        int v = (i < N_NODES) ? deg[i] : 0;
        int incl = v;
#pragma unroll
        for (int s = 1; s < 64; s <<= 1) {
            int t = __shfl_up(incl, s);
            if (lane >= s) incl += t;
        }
        if (lane == 63) wsum[wid] = incl;
        __syncthreads();
        if (wid == 0) {
            int wv = (lane < 16) ? wsum[lane] : 0;
            int wincl = wv;
#pragma unroll
            for (int s = 1; s < 16; s <<= 1) {
                int t = __shfl_up(wincl, s);
                if (lane >= s) wincl += t;
            }
            if (lane < 16) wsum[lane] = wincl - wv;
        }
        __syncthreads();
        int excl = s_carry + wsum[wid] + incl - v;
        if (i < N_NODES) offs[i] = excl;
        __syncthreads();
        if (threadIdx.x == 1023) s_carry = excl + v;
        __syncthreads();
    }
    if (threadIdx.x == 0) offs[N_NODES] = E_EDGES;
}

__global__ void k_place(const int* __restrict__ src, const int* __restrict__ dst,
                        const int* __restrict__ etype, const int* __restrict__ offs,
                        int* __restrict__ cursor, int* __restrict__ ekey) {
    int e = blockIdx.x * blockDim.x + threadIdx.x;
    if (e < E_EDGES) {
        int d = dst[e];
        int p = atomicAdd(&cursor[d], 1);
        ekey[offs[d] + p] = (etype[e] << 16) | src[e];
    }
}

__global__ void k_sort(const int* __restrict__ offs, int* __restrict__ ekey) {
    int i = blockIdx.x * blockDim.x + threadIdx.x;
    if (i >= N_NODES) return;
    int lo = offs[i], hi = offs[i + 1];
    for (int a = lo + 1; a < hi; a++) {
        int k = ekey[a];
        int b = a - 1;
        while (b >= lo && ekey[b] > k) { ekey[b + 1] = ekey[b]; b--; }
        ekey[b + 1] = k;
    }
}

__global__ void k_segs(const int* __restrict__ offs, const int* __restrict__ ekey,
                       int* __restrict__ relOffs) {
    int i = blockIdx.x * blockDim.x + threadIdx.x;
    if (i >= N_NODES) return;
    int lo = offs[i], hi = offs[i + 1];
    int p = lo;
    relOffs[i * 9] = lo;
#pragma unroll
    for (int r = 0; r < NREL; r++) {
        while (p < hi && (ekey[p] >> 16) == r) p++;
        relOffs[i * 9 + r + 1] = p;
    }
}

// ---------------------------------------------------------------------------
// Conversions: x -> bf16; weights -> transposed bf16 Wt[c][k] (root fused as
// leading K block).
// ---------------------------------------------------------------------------
__global__ void k_cvt_x(const float* __restrict__ x, unsigned short* __restrict__ xb,
                        int n4) {
    int i = blockIdx.x * blockDim.x + threadIdx.x;
    if (i >= n4) return;
    float4 v = *(const float4*)&x[i * 4];
    short4 o;
    o.x = (short)f2bf(v.x); o.y = (short)f2bf(v.y);
    o.z = (short)f2bf(v.z); o.w = (short)f2bf(v.w);
    *(short4*)&xb[i * 4] = o;
}

__global__ void k_wt1(const float* __restrict__ root1, const float* __restrict__ W1,
                      unsigned short* __restrict__ Wt) {
    int idx = blockIdx.x * blockDim.x + threadIdx.x;
    if (idx >= 256 * 1152) return;
    int c = idx / 1152, k = idx % 1152;
    float v = (k < IN_CH) ? root1[k * 256 + c] : W1[(size_t)(k - IN_CH) * 256 + c];
    Wt[idx] = f2bf(v);
}

__global__ void k_wt2(const float* __restrict__ root2, const float* __restrict__ W2,
                      unsigned short* __restrict__ Wt) {
    int idx = blockIdx.x * blockDim.x + threadIdx.x;
    if (idx >= 256 * 2304) return;
    int c = idx / 2304, k = idx % 2304;
    float v = (k < HID) ? root2[k * 256 + c] : W2[(size_t)(k - HID) * 256 + c];
    Wt[idx] = f2bf(v);
}

// ---------------------------------------------------------------------------
// Full-relation mean aggregation, one wave per node, lane owns CH/64
// channels. Keys for each relation segment are preloaded cooperatively
// (1 coalesced load) and broadcast via __shfl, so gather addresses never
// depend on an in-flight load; edge loop unrolled x4 -> 4 gathers in flight.
// ---------------------------------------------------------------------------
template <int CH>
__global__ __launch_bounds__(256) void k_agg8(const unsigned short* __restrict__ xin,
                                              const int* __restrict__ relOffs,
                                              const int* __restrict__ ekey,
                                              unsigned short* __restrict__ agg,
                                              int base, int count) {
    const int w = threadIdx.x >> 6;
    const int t = threadIdx.x & 63;
    const int rel_node = blockIdx.x * 4 + w;
    if (rel_node >= count) return;
    const int node = base + rel_node;
    constexpr int VPT = CH / 64;  // 4 (CH=256) or 2 (CH=128)
    const unsigned short* xcol = xin + t * VPT;
    unsigned short* orow = agg + (size_t)rel_node * (NREL * CH) + t * VPT;
    const int* ro = relOffs + node * 9;
#pragma unroll
    for (int r = 0; r < NREL; r++) {
        const int s = ro[r], e = ro[r + 1];
        const int len = e - s;
        float a0 = 0.f, a1 = 0.f, a2 = 0.f, a3 = 0.f;
        for (int cs = s; cs < e; cs += 64) {
            const int clen = (e - cs < 64) ? (e - cs) : 64;
            const int kv = ekey[cs + ((t < clen) ? t : (clen - 1))];
            for (int j = 0; j < clen; j += 4) {
                const int i1 = (j + 1 < clen) ? j + 1 : clen - 1;
                const int i2 = (j + 2 < clen) ? j + 2 : clen - 1;
                const int i3 = (j + 3 < clen) ? j + 3 : clen - 1;
                const int k0 = __shfl(kv, j) & 0xFFFF;
                const int k1 = __shfl(kv, i1) & 0xFFFF;
                const int k2 = __shfl(kv, i2) & 0xFFFF;
                const int k3 = __shfl(kv, i3) & 0xFFFF;
                const bool b1 = (j + 1 < clen), b2 = (j + 2 < clen), b3 = (j + 3 < clen);
                if (VPT == 4) {
                    short4 v0 = *(const short4*)(xcol + (size_t)k0 * CH);
                    short4 v1 = *(const short4*)(xcol + (size_t)k1 * CH);
                    short4 v2 = *(const short4*)(xcol + (size_t)k2 * CH);
                    short4 v3 = *(const short4*)(xcol + (size_t)k3 * CH);
                    a0 += bf2f((unsigned short)v0.x);
                    a1 += bf2f((unsigned short)v0.y);
                    a2 += bf2f((unsigned short)v0.z);
                    a3 += bf2f((unsigned short)v0.w);
                    a0 += b1 ? bf2f((unsigned short)v1.x) : 0.f;
                    a1 += b1 ? bf2f((unsigned short)v1.y) : 0.f;
                    a2 += b1 ? bf2f((unsigned short)v1.z) : 0.f;
                    a3 += b1 ? bf2f((unsigned short)v1.w) : 0.f;
                    a0 += b2 ? bf2f((unsigned short)v2.x) : 0.f;
                    a1 += b2 ? bf2f((unsigned short)v2.y) : 0.f;
                    a2 += b2 ? bf2f((unsigned short)v2.z) : 0.f;
                    a3 += b2 ? bf2f((unsigned short)v2.w) : 0.f;
                    a0 += b3 ? bf2f((unsigned short)v3.x) : 0.f;
                    a1 += b3 ? bf2f((unsigned short)v3.y) : 0.f;
                    a2 += b3 ? bf2f((unsigned short)v3.z) : 0.f;
                    a3 += b3 ? bf2f((unsigned short)v3.w) : 0.f;
                } else {
                    short2 v0 = *(const short2*)(xcol + (size_t)k0 * CH);
                    short2 v1 = *(const short2*)(xcol + (size_t)k1 * CH);
                    short2 v2 = *(const short2*)(xcol + (size_t)k2 * CH);
                    short2 v3 = *(const short2*)(xcol + (size_t)k3 * CH);
                    a0 += bf2f((unsigned short)v0.x);
                    a1 += bf2f((unsigned short)v0.y);
                    a0 += b1 ? bf2f((unsigned short)v1.x) : 0.f;
                    a1 += b1 ? bf2f((unsigned short)v1.y) : 0.f;
                    a0 += b2 ? bf2f((unsigned short)v2.x) : 0.f;
                    a1 += b2 ? bf2f((unsigned short)v2.y) : 0.f;
                    a0 += b3 ? bf2f((unsigned short)v3.x) : 0.f;
                    a1 += b3 ? bf2f((unsigned short)v3.y) : 0.f;
                }
            }
        }
        const float inv = (len > 0) ? 1.0f / (float)len : 0.0f;
        if (VPT == 4) {
            short4 o;
            o.x = (short)f2bf(a0 * inv);
            o.y = (short)f2bf(a1 * inv);
            o.z = (short)f2bf(a2 * inv);
            o.w = (short)f2bf(a3 * inv);
            *(short4*)(orow + (size_t)r * CH) = o;
        } else {
            short2 o;
            o.x = (short)f2bf(a0 * inv);
            o.y = (short)f2bf(a1 * inv);
            *(short2*)(orow + (size_t)r * CH) = o;
        }
    }
}

// ---------------------------------------------------------------------------
// bf16 MFMA GEMM: hbOut[M,256] = relu([Aroot | Aagg] @ Wt-slice + bias).
// Tile 128x128, BK=64, 4 waves, XOR-swizzled LDS staged via global_load_lds.
// Grid: 1-D, 16*rowsPerXcd blocks; bijective XCD swizzle so both col-blocks
// of a row-panel land on the same XCD 8 dispatch slots apart (A-panel read
// from HBM once, second read L2-hit). Holes (row >= nRow) early-exit.
// ---------------------------------------------------------------------------
__global__ __launch_bounds__(256) void k_mgemm(
    const unsigned short* __restrict__ Aroot, int rootK, int ldroot,
    const unsigned short* __restrict__ Aagg, int ldagg,
    const unsigned short* __restrict__ Wt, int ldWt, int Ktot,
    const float* __restrict__ bias, unsigned short* __restrict__ hbOut, int M) {
    __shared__ __align__(16) unsigned short Al[128 * 64];
    __shared__ __align__(16) unsigned short Bl[128 * 64];
    const int rowsPerXcd = gridDim.x >> 4;
    const int p = blockIdx.x;
    const int xcd = p & 7;
    const int col = (p >> 3) & 1;
    const int rIdx = p >> 4;
    const int row = xcd * rowsPerXcd + rIdx;
    if (row * 128 >= M) return;
    const int bm = row * 128;
    const int bn = col * 128;
    const int tid = threadIdx.x;
    const int wv = tid >> 6, ln = tid & 63;
    const int wr = (wv & 1) * 64;
    const int wc = (wv >> 1) * 64;
    const int lg = ln >> 4;
    const int lr = ln & 15;

    f32x4 acc[4][4];
#pragma unroll
    for (int m = 0; m < 4; m++)
#pragma unroll
        for (int n = 0; n < 4; n++) acc[m][n] = (f32x4){0.f, 0.f, 0.f, 0.f};

    int baseR[4], baseG[4], baseB[4];
#pragma unroll
    for (int q = 0; q < 4; q++) {
        int t = (wv * 4 + q) * 64 + ln;
        int r = t >> 3, ps = t & 7;
        int slog = ps ^ (r & 7);
        int rg = bm + r; if (rg > M - 1) rg = M - 1;
        baseR[q] = (rootK > 0) ? (rg * ldroot + slog * 8) : 0;
        baseG[q] = rg * ldagg + slog * 8 - rootK;
        baseB[q] = (bn + r) * ldWt + slog * 8;
    }

    for (int k0 = 0; k0 < Ktot; k0 += 64) {
        __syncthreads();
        const bool inRoot = (k0 < rootK);
#pragma unroll
        for (int q = 0; q < 4; q++) {
            const unsigned short* sa =
                inRoot ? (Aroot + baseR[q] + k0) : (Aagg + baseG[q] + k0);
            gload_lds16(sa, &Al[(wv * 4 + q) * 512]);
        }
#pragma unroll
        for (int q = 0; q < 4; q++) {
            gload_lds16(Wt + baseB[q] + k0, &Bl[(wv * 4 + q) * 512]);
        }
        asm volatile("s_waitcnt vmcnt(0)" ::: "memory");
        __syncthreads();
#pragma unroll
        for (int kk = 0; kk < 2; kk++) {
            bf16x8 af[4], bfr[4];
#pragma unroll
            for (int m = 0; m < 4; m++) {
                int r = wr + 16 * m + lr;
                int ph = (kk * 4 + lg) ^ (r & 7);
                af[m] = *(const bf16x8*)&Al[r * 64 + ph * 8];
            }
#pragma unroll
            for (int n = 0; n < 4; n++) {
                int c = wc + 16 * n + lr;
                int ph = (kk * 4 + lg) ^ (c & 7);
                bfr[n] = *(const bf16x8*)&Bl[c * 64 + ph * 8];
            }
#pragma unroll
            for (int m = 0; m < 4; m++)
#pragma unroll
                for (int n = 0; n < 4; n++)
                    acc[m][n] = __builtin_amdgcn_mfma_f32_16x16x32_bf16(
                        af[m], bfr[n], acc[m][n], 0, 0, 0);
        }
    }

    // C/D: col = lane&15, row = (lane>>4)*4 + reg  [m89/m91]
#pragma unroll
    for (int m = 0; m < 4; m++) {
#pragma unroll
        for (int reg = 0; reg < 4; reg++) {
            int r = bm + wr + 16 * m + lg * 4 + reg;
            if (r >= M) continue;
#pragma unroll
            for (int n = 0; n < 4; n++) {
                int c = bn + wc + 16 * n + lr;
                float v = acc[m][n][reg] + bias[c];
                hbOut[(size_t)r * 256 + c] = f2bf(fmaxf(v, 0.f));
            }
        }
    }
}

// ---------------------------------------------------------------------------
// Final linear [256->64] (bf16 h in, fp32 W) + fused log_softmax.
// ---------------------------------------------------------------------------
__global__ __launch_bounds__(256) void k_final2(const unsigned short* __restrict__ h,
                                                const float* __restrict__ W,
                                                const float* __restrict__ bias,
                                                float* __restrict__ out, int M) {
    __shared__ __align__(16) float Ws[128][OUT_CH];
    __shared__ __align__(16) float As[8][128];
    const int tid = threadIdx.x;
    const int tx = tid & 15;
    const int ty = tid >> 4;
    const int bm = blockIdx.x * 128;
    const int arow = tid >> 1;
    const int acol = (tid & 1) * 4;
    const bool aval = (bm + arow) < M;
    float acc[8][4] = {};

    for (int half = 0; half < 2; half++) {
        __syncthreads();
        for (int i = tid * 4; i < 128 * OUT_CH; i += 1024)
            *(float4*)((float*)Ws + i) = *(const float4*)(W + half * 128 * OUT_CH + i);
        for (int k0 = 0; k0 < 128; k0 += 8) {
            float4 av = make_float4(0.f, 0.f, 0.f, 0.f);
            if (aval) {
                short4 hv = *(const short4*)&h[(size_t)(bm + arow) * HID + half * 128 + k0 + acol];
                av.x = bf2f((unsigned short)hv.x);
                av.y = bf2f((unsigned short)hv.y);
                av.z = bf2f((unsigned short)hv.z);
                av.w = bf2f((unsigned short)hv.w);
            }
            __syncthreads();
            As[acol + 0][arow] = av.x;
            As[acol + 1][arow] = av.y;
            As[acol + 2][arow] = av.z;
            As[acol + 3][arow] = av.w;
            __syncthreads();
#pragma unroll
            for (int k = 0; k < 8; k++) {
                float a[8];
                *(float4*)&a[0] = *(const float4*)&As[k][ty * 8];
                *(float4*)&a[4] = *(const float4*)&As[k][ty * 8 + 4];
                float4 wv = *(const float4*)&Ws[k0 + k][tx * 4];
#pragma unroll
                for (int i = 0; i < 8; i++) {
                    acc[i][0] += a[i] * wv.x;
                    acc[i][1] += a[i] * wv.y;
                    acc[i][2] += a[i] * wv.z;
                    acc[i][3] += a[i] * wv.w;
                }
            }
        }
    }

    const float4 bv = *(const float4*)&bias[tx * 4];
#pragma unroll
    for (int i = 0; i < 8; i++) {
        int row = bm + ty * 8 + i;
        float v0 = acc[i][0] + bv.x;
        float v1 = acc[i][1] + bv.y;
        float v2 = acc[i][2] + bv.z;
        float v3 = acc[i][3] + bv.w;
        float m = fmaxf(fmaxf(v0, v1), fmaxf(v2, v3));
#pragma unroll
        for (int s = 1; s < 16; s <<= 1) m = fmaxf(m, __shfl_xor(m, s));
        float sum = expf(v0 - m) + expf(v1 - m) + expf(v2 - m) + expf(v3 - m);
#pragma unroll
        for (int s = 1; s < 16; s <<= 1) sum += __shfl_xor(sum, s);
        float lse = m + logf(sum);
        if (row < M) {
            float4 o;
            o.x = v0 - lse; o.y = v1 - lse; o.z = v2 - lse; o.w = v3 - lse;
            *(float4*)&out[(size_t)row * OUT_CH + tx * 4] = o;
        }
    }
}

// ---------------------------------------------------------------------------
extern "C" void kernel_launch(void* const* d_in, const int* in_sizes, int n_in,
                              void* d_out, int out_size, void* d_ws, size_t ws_size,
                              hipStream_t stream) {
    const float* x     = (const float*)d_in[0];
    const int*   eidx  = (const int*)d_in[1];
    const int*   etype = (const int*)d_in[2];
    const float* W1    = (const float*)d_in[3];
    const float* root1 = (const float*)d_in[4];
    const float* b1    = (const float*)d_in[5];
    const float* W2    = (const float*)d_in[6];
    const float* root2 = (const float*)d_in[7];
    const float* b2    = (const float*)d_in[8];
    const float* linW  = (const float*)d_in[9];
    const float* linb  = (const float*)d_in[10];
    float* out = (float*)d_out;
    const int* srcI = eidx;
    const int* dstI = eidx + E_EDGES;

    char* ws = (char*)d_ws;
    size_t off = 0;
    auto alloc = [&](size_t bytes) {
        size_t o = off;
        off += (bytes + 255) & ~(size_t)255;
        return ws + o;
    };
    unsigned short* xb   = (unsigned short*)alloc((size_t)N_NODES * IN_CH * 2);
    unsigned short* hb1  = (unsigned short*)alloc((size_t)N_NODES * HID * 2);
    unsigned short* hb2  = (unsigned short*)alloc((size_t)N_NODES * HID * 2);
    unsigned short* Wt1  = (unsigned short*)alloc((size_t)256 * 1152 * 2);
    unsigned short* Wt2  = (unsigned short*)alloc((size_t)256 * 2304 * 2);
    int* deg     = (int*)alloc((size_t)N_NODES * 4);
    int* cursor  = (int*)alloc((size_t)N_NODES * 4);
    int* offs    = (int*)alloc((size_t)(N_NODES + 1) * 4);
    int* ekey    = (int*)alloc((size_t)E_EDGES * 4);
    int* relOffs = (int*)alloc((size_t)N_NODES * 9 * 4);
    // agg buffer: max(50000 x 8*128, 25000 x 8*256) bf16 = 102.4 MB
    unsigned short* agg = (unsigned short*)alloc((size_t)N_NODES * NREL * IN_CH * 2);

    // conversions + CSR
    k_cvt_x<<<(N_NODES * IN_CH / 4 + 255) / 256, 256, 0, stream>>>(x, xb, N_NODES * IN_CH / 4);
    k_wt1<<<(256 * 1152 + 255) / 256, 256, 0, stream>>>(root1, W1, Wt1);
    k_wt2<<<(256 * 2304 + 255) / 256, 256, 0, stream>>>(root2, W2, Wt2);
    hipMemsetAsync(deg, 0, (size_t)N_NODES * 4, stream);
    hipMemsetAsync(cursor, 0, (size_t)N_NODES * 4, stream);
    k_deg<<<(E_EDGES + 255) / 256, 256, 0, stream>>>(dstI, deg);
    k_scan<<<1, 1024, 0, stream>>>(deg, offs);
    k_place<<<(E_EDGES + 255) / 256, 256, 0, stream>>>(srcI, dstI, etype, offs, cursor, ekey);
    k_sort<<<(N_NODES + 255) / 256, 256, 0, stream>>>(offs, ekey);
    k_segs<<<(N_NODES + 255) / 256, 256, 0, stream>>>(offs, ekey, relOffs);

    auto gemmGrid = [](int M) {
        int nRow = (M + 127) / 128;
        int rowsPerXcd = (nRow + 7) / 8;
        return 16 * rowsPerXcd;
    };

    // ---- Layer 1: agg (one pass) + one fused GEMM, K = 128 + 1024 ----
    k_agg8<IN_CH><<<(N_NODES + 3) / 4, 256, 0, stream>>>(xb, relOffs, ekey, agg, 0, N_NODES);
    k_mgemm<<<gemmGrid(N_NODES), 256, 0, stream>>>(xb, IN_CH, IN_CH, agg, NREL * IN_CH,
                                                   Wt1, 1152, 1152, b1, hb1, N_NODES);

    // ---- Layer 2: two M-chunks, each agg (one pass) + one fused GEMM,
    //      K = 256 + 2048 ----
    for (int c = 0; c < 2; c++) {
        const int base = c * CHUNK;
        const int cnt = (base + CHUNK <= N_NODES) ? CHUNK : (N_NODES - base);
        k_agg8<HID><<<(cnt + 3) / 4, 256, 0, stream>>>(hb1, relOffs, ekey, agg, base, cnt);
        k_mgemm<<<gemmGrid(cnt), 256, 0, stream>>>(hb1 + (size_t)base * HID, HID, HID,
                                                   agg, NREL * HID, Wt2, 2304, 2304, b2,
                                                   hb2 + (size_t)base * HID, cnt);
    }

    // ---- Final linear + log_softmax ----
    k_final2<<<(N_NODES + 127) / 128, 256, 0, stream>>>(hb2, linW, linb, out, N_NODES);
}